// Round 8
// baseline (511.959 us; speedup 1.0000x reference)
//
#include <hip/hip_runtime.h>
#include <hip/hip_bf16.h>
#include <stdint.h>

#define B_ROWS 4096
#define IN_F   4096
#define OUT_F  4096

// 256x256 tile, K-step 64, 8 waves (512 threads).
#define BM 256
#define BN 256
#define BK 64
#define NKT (IN_F / BK)   // 64 K-tiles

typedef float  f32x4  __attribute__((ext_vector_type(4)));
typedef short  bf16x8 __attribute__((ext_vector_type(8)));
typedef unsigned short u16x4 __attribute__((ext_vector_type(4)));

#define AS1 __attribute__((address_space(1)))
#define AS3 __attribute__((address_space(3)))

template<int N> struct IC { static constexpr int v = N; };

__device__ __forceinline__ uint16_t f2bf_rne(float f) {
    uint32_t u = __float_as_uint(f);
    uint32_t r = u + 0x7fffu + ((u >> 16) & 1u);
    return (uint16_t)(r >> 16);
}
__device__ __forceinline__ float bf2f(uint16_t h) {
    return __uint_as_float(((uint32_t)h) << 16);
}

// ---------------------------------------------------------------------------
// Fused prep (R5 v3, unchanged):
//   blocks [0, 4096):     x fp32 -> xb bf16 [b][k] and xbT bf16 [k][b]
//   blocks [4096, 6144):  w fp32 + mask -> masked bf16 wb, grid-stride
// ---------------------------------------------------------------------------
__global__ __launch_bounds__(256) void prep_kernel(
    const float* __restrict__ x, uint16_t* __restrict__ xb, uint16_t* __restrict__ xbT,
    const float* __restrict__ w, const void* __restrict__ mraw, uint16_t* __restrict__ wb)
{
    const int tid = threadIdx.x;
    const int blk = blockIdx.x;

    if (blk < 4096) {
        __shared__ float t[64][65];
        const int r0 = (blk >> 6) * 64;   // batch rows
        const int c0 = (blk & 63) * 64;   // feature cols
        const int lr = tid >> 4;          // 0..15
        const int lc4 = (tid & 15) * 4;   // 0..60

#pragma unroll
        for (int p = 0; p < 4; ++p) {
            const int row = p * 16 + lr;
            float4 v = *(const float4*)(x + (size_t)(r0 + row) * IN_F + c0 + lc4);
            ushort4 o;
            o.x = f2bf_rne(v.x); o.y = f2bf_rne(v.y);
            o.z = f2bf_rne(v.z); o.w = f2bf_rne(v.w);
            *(ushort4*)(xb + (size_t)(r0 + row) * IN_F + c0 + lc4) = o;
            t[row][lc4 + 0] = v.x; t[row][lc4 + 1] = v.y;
            t[row][lc4 + 2] = v.z; t[row][lc4 + 3] = v.w;
        }
        __syncthreads();
#pragma unroll
        for (int p = 0; p < 4; ++p) {
            const int c = p * 16 + lr;    // source col -> dest row
            ushort4 o;
            o.x = f2bf_rne(t[lc4 + 0][c]);
            o.y = f2bf_rne(t[lc4 + 1][c]);
            o.z = f2bf_rne(t[lc4 + 2][c]);
            o.w = f2bf_rne(t[lc4 + 3][c]);
            *(ushort4*)(xbT + (size_t)(c0 + c) * B_ROWS + r0 + lc4) = o;
        }
    } else {
        __shared__ int wflag[4];
        uint32_t mword = ((const uint32_t*)mraw)[tid];           // words 0..255, L2-hot
        unsigned long long bal = __ballot((mword & 0xFFFFFF00u) != 0);
        if ((tid & 63) == 0) wflag[tid >> 6] = (bal != 0ull);
        __syncthreads();
        const int flag = wflag[0] | wflag[1] | wflag[2] | wflag[3];

        // grid-stride over 8192 chunks of 2048 elems; 2048 blocks -> 4 iters.
#pragma unroll
        for (int it = 0; it < 4; ++it) {
            const size_t c = (size_t)(blk - 4096) + (size_t)it * 2048;
            const size_t e = c * 2048 + (size_t)tid * 8;
            float4 v0 = *(const float4*)(w + e);
            float4 v1 = *(const float4*)(w + e + 4);
            int m[8];
            if (flag) {   // 1-byte bool mask
                uint2 mm = *(const uint2*)((const uint8_t*)mraw + e);
#pragma unroll
                for (int j = 0; j < 4; ++j) m[j]     = (mm.x >> (8 * j)) & 0xff;
#pragma unroll
                for (int j = 0; j < 4; ++j) m[4 + j] = (mm.y >> (8 * j)) & 0xff;
            } else {      // int32 0/1 mask
                const int* mp = (const int*)mraw + e;
                int4 a = *(const int4*)mp;
                int4 b = *(const int4*)(mp + 4);
                m[0] = a.x; m[1] = a.y; m[2] = a.z; m[3] = a.w;
                m[4] = b.x; m[5] = b.y; m[6] = b.z; m[7] = b.w;
            }
            bf16x8 o;
            o[0] = m[0] ? (short)f2bf_rne(v0.x) : (short)0;
            o[1] = m[1] ? (short)f2bf_rne(v0.y) : (short)0;
            o[2] = m[2] ? (short)f2bf_rne(v0.z) : (short)0;
            o[3] = m[3] ? (short)f2bf_rne(v0.w) : (short)0;
            o[4] = m[4] ? (short)f2bf_rne(v1.x) : (short)0;
            o[5] = m[5] ? (short)f2bf_rne(v1.y) : (short)0;
            o[6] = m[6] ? (short)f2bf_rne(v1.z) : (short)0;
            o[7] = m[7] ? (short)f2bf_rne(v1.w) : (short)0;
            *(bf16x8*)(wb + e) = o;
        }
    }
}

// ds_read_b128 with compile-time offset immediate. Early-clobber dst:
// must never share registers with the address operand (in-flight load).
#define DSR(dst, base, OFS) \
    asm volatile("ds_read_b128 %0, %1 offset:" #OFS : "=&v"(dst) : "v"(base))
// global_load_dwordx4 -> 4 VGPR (A fragment). Early-clobber dst: R7 crash
// root-cause #1 was dst/addr register overlap on an in-flight load.
#define GLD(dst, p, OFS) \
    asm volatile("global_load_dwordx4 %0, %1, off offset:" #OFS : "=&v"(dst) : "v"(p))
#define LDSOFF(p) ((uint32_t)(uintptr_t)(AS3 void*)(p))
#define SB() __builtin_amdgcn_sched_barrier(0)

// ---------------------------------------------------------------------------
// 256x256x64 GEMM, A direct global->VGPR, B via LDS (swizzled, dbuf).
// C[b,o] = relu( sum_k xb[b,k]*wb[o,k] + bias[o] ) + xbT[rc[o]][b]
//
// R6 analysis: previous structure pinned at ~127us by LDS read BW (192KB/
// tile: A-halves read 4x, B-slices 2x ~ 2300-2700 cyc/tile vs MFMA 2480).
// Fix: A fragments load straight from row-major xb (16 rows x 64B
// contiguous per wave-load => 16 global_load_dwordx4 /wave/tile, L1/L2-
// served redundancy); LDS keeps only B (64KB read/tile, staging halves).
//
// Per-wave vm ledger (A0..A3 = 4-frag A groups, Bst = 4 B-stage loads;
// oldest-first retirement; invariant at tile entry: [A0(4)]):
//   TOP  s_barrier                       (B(t) visible; own stages retired g3)
//   g1   issue ds b(8) | A1(4) | Bst(4) -> [A0,A1,Bst]
//        vmcnt(8): A0 ready   lgkm(4): b_ks0 ready      -> blk0 (a0 x b)
//   g2   issue A2(4) -> [A1,Bst,A2]
//        vmcnt(8): A1 ready                             -> blk1 (a1 x b)
//   g3   issue A3(4) -> [Bst,A2,A3]
//        vmcnt(4): Bst+A2 ready   lgkm(0): b2 ready     -> blk2 (a2 x b2)
//   g4   advance ptrs; issue A0'(t+1) -> [A3,A0']
//        vmcnt(4): A3 ready                             -> blk3 (a3 x b2)
// No wait ever drains young loads; one barrier per tile; setprio on MFMA.
// R7 crash root-cause #2: the final tile's A0' ghost loads stayed in
// flight across the epilogue; the allocator reused their dst VGPRs, then
// the landing data clobbered epilogue state. Fixed: full vmcnt/lgkm drain
// immediately after the K-loop (one-time, ~free).
// ---------------------------------------------------------------------------
__global__ __launch_bounds__(512, 2) void gemm_kernel(
    const uint16_t* __restrict__ xb, const uint16_t* __restrict__ wb,
    const uint16_t* __restrict__ xbT, const float* __restrict__ bias,
    const int* __restrict__ rc, float* __restrict__ out)
{
    __shared__ alignas(16) uint16_t Bbuf[2][2][128 * BK];   // 64 KB (B only)
    __shared__ float bias_s[BN];
    __shared__ int   rc_s[BN];

    const int tid = threadIdx.x;

    // XCD-aware bijective swizzle: 256 blocks, 8 XCDs.
    const int bid = blockIdx.x;
    const int wg  = (bid & 7) * 32 + (bid >> 3);
    const int row0 = (wg >> 4) * BM;
    const int col0 = (wg & 15) * BN;

    const int wave = tid >> 6, lane = tid & 63;
    const int wm = wave >> 2;          // 0..1 : which 128-row A half
    const int wn = wave & 3;           // 0..3 : 64-col B slice
    const int bh = wn >> 1;            // which 128-col B half
    const int quad = lane >> 4, l16 = lane & 15;
    const int swr = (l16 & 7) << 3;
    const int e0  = (quad << 3) ^ swr;                    // elem offset, ks=0
    const uint32_t kd = (uint32_t)(((e0 ^ 32) - e0) * 2); // byte delta ks0->ks1

    // B LDS read bases per dbuf parity (verified conflict-free pattern).
    const uint32_t bB0  = LDSOFF(&Bbuf[0][bh][0]) + (uint32_t)((((wn & 1) * 64 + l16) * BK + e0) * 2);
    const uint32_t bB1  = LDSOFF(&Bbuf[1][bh][0]) + (uint32_t)((((wn & 1) * 64 + l16) * BK + e0) * 2);
    const uint32_t bB0k = bB0 + kd, bB1k = bB1 + kd;

    // B staging source (pre-swizzled global address, rule 21).
    const int srow = tid >> 3;                              // 0..63
    const int ssw  = ((tid & 7) ^ (srow & 7)) << 3;         // element offset
    const uint16_t* pB0 = wb + (size_t)(col0 + srow) * IN_F + ssw;
    const uint16_t* pB1 = pB0 + (size_t)128 * IN_F;

    auto stage = [&](const uint16_t* src, uint16_t* ldsdst, size_t ko) {
        __builtin_amdgcn_global_load_lds((const AS1 void*)(src + ko),
                                         (AS3 void*)(ldsdst + tid * 8), 16, 0, 0);
        __builtin_amdgcn_global_load_lds((const AS1 void*)(src + ko + (size_t)64 * IN_F),
                                         (AS3 void*)(ldsdst + tid * 8 + 4096), 16, 0, 0);
    };

    // A fragment pointers: 8 rows-of-16 bases; lane reads 16B at
    // row = row0 + wm*128 + m*16 + l16, k-chunk = quad*8 (+ks*32, +t*64).
    const uint16_t* paB = xb + (size_t)(row0 + wm * 128 + l16) * IN_F + quad * 8;
    const uint16_t* pa0 = paB;
    const uint16_t* pa1 = paB + (size_t)16 * IN_F;
    const uint16_t* pa2 = paB + (size_t)32 * IN_F;
    const uint16_t* pa3 = paB + (size_t)48 * IN_F;
    const uint16_t* pa4 = paB + (size_t)64 * IN_F;
    const uint16_t* pa5 = paB + (size_t)80 * IN_F;
    const uint16_t* pa6 = paB + (size_t)96 * IN_F;
    const uint16_t* pa7 = paB + (size_t)112 * IN_F;

    f32x4 acc[8][4];   // [mi][ni]
#pragma unroll
    for (int mi = 0; mi < 8; ++mi)
#pragma unroll
        for (int ni = 0; ni < 4; ++ni)
            acc[mi][ni] = (f32x4){0.f, 0.f, 0.f, 0.f};

    bf16x8 a0[4], a1[4], a2[4], a3[4], b[4], b2[4];

    // ---- Prologue: bias/rc + stage B(t0) + A0(t0); leave exactly [A0(4)].
    if (tid < BN) {
        __builtin_amdgcn_global_load_lds((const AS1 void*)(bias + col0 + tid),
                                         (AS3 void*)(bias_s + tid), 4, 0, 0);
        __builtin_amdgcn_global_load_lds((const AS1 void*)(rc + col0 + tid),
                                         (AS3 void*)(rc_s + tid), 4, 0, 0);
    }
    stage(pB0, &Bbuf[0][0][0], 0);
    stage(pB1, &Bbuf[0][1][0], 0);
    SB();
    GLD(a0[0], pa0, 0); GLD(a0[1], pa1, 0); GLD(a0[2], pa2, 0); GLD(a0[3], pa3, 0);
    asm volatile("s_waitcnt vmcnt(4)" ::: "memory");   // bias/rc/Bst done; A0 in flight
    SB();
    __builtin_amdgcn_s_barrier();

#define WAITV(n) do { asm volatile("s_waitcnt vmcnt(" #n ")" ::: "memory"); SB(); } while (0)
#define WAITL(n) do { asm volatile("s_waitcnt lgkmcnt(" #n ")" ::: "memory"); SB(); } while (0)

    auto tile = [&](auto curc, int t) {
        constexpr int CUR = decltype(curc)::v;
        constexpr int NXT = CUR ^ 1;
        const uint32_t bB  = CUR ? bB1  : bB0;
        const uint32_t bBk = CUR ? bB1k : bB0k;
        // t = NKT-1 stages/loads one K-step past the end; lands in adjacent
        // workspace regions, never consumed.
        const size_t koff = (size_t)(t + 1) * BK;

        // ---- g1: all B ds_reads; A1; stage B(t+1).
        DSR(b[0],  bB,  0); DSR(b[1],  bB,  2048); DSR(b[2],  bB,  4096); DSR(b[3],  bB,  6144);
        DSR(b2[0], bBk, 0); DSR(b2[1], bBk, 2048); DSR(b2[2], bBk, 4096); DSR(b2[3], bBk, 6144);
        GLD(a1[0], pa4, 0); GLD(a1[1], pa5, 0); GLD(a1[2], pa6, 0); GLD(a1[3], pa7, 0);
        SB();                                   // pin order: A1 before Bst
        stage(pB0, &Bbuf[NXT][0][0], koff);
        stage(pB1, &Bbuf[NXT][1][0], koff);

        WAITV(8);   // A0 ready; [A1,Bst] in flight
        WAITL(4);   // b(ks0) ready
        __builtin_amdgcn_s_setprio(1);
#pragma unroll
        for (int m = 0; m < 4; ++m)
#pragma unroll
            for (int ni = 0; ni < 4; ++ni)
                acc[m][ni] = __builtin_amdgcn_mfma_f32_16x16x32_bf16(a0[m], b[ni], acc[m][ni], 0, 0, 0);
        __builtin_amdgcn_s_setprio(0);

        // ---- g2: A2 (ks1, mi0-3).
        GLD(a2[0], pa0, 64); GLD(a2[1], pa1, 64); GLD(a2[2], pa2, 64); GLD(a2[3], pa3, 64);
        WAITV(8);   // A1 ready; [Bst,A2] in flight
        __builtin_amdgcn_s_setprio(1);
#pragma unroll
        for (int m = 0; m < 4; ++m)
#pragma unroll
            for (int ni = 0; ni < 4; ++ni)
                acc[4 + m][ni] = __builtin_amdgcn_mfma_f32_16x16x32_bf16(a1[m], b[ni], acc[4 + m][ni], 0, 0, 0);
        __builtin_amdgcn_s_setprio(0);

        // ---- g3: A3 (ks1, mi4-7).
        GLD(a3[0], pa4, 64); GLD(a3[1], pa5, 64); GLD(a3[2], pa6, 64); GLD(a3[3], pa7, 64);
        WAITV(4);   // Bst + A2 ready; [A3] in flight
        WAITL(0);   // b2(ks1) ready
        __builtin_amdgcn_s_setprio(1);
#pragma unroll
        for (int m = 0; m < 4; ++m)
#pragma unroll
            for (int ni = 0; ni < 4; ++ni)
                acc[m][ni] = __builtin_amdgcn_mfma_f32_16x16x32_bf16(a2[m], b2[ni], acc[m][ni], 0, 0, 0);
        __builtin_amdgcn_s_setprio(0);

        // ---- g4: advance A pointers; prefetch A0'(t+1).
        pa0 += BK; pa1 += BK; pa2 += BK; pa3 += BK;
        pa4 += BK; pa5 += BK; pa6 += BK; pa7 += BK;
        GLD(a0[0], pa0, 0); GLD(a0[1], pa1, 0); GLD(a0[2], pa2, 0); GLD(a0[3], pa3, 0);
        WAITV(4);   // A3 ready; [A0'] carried to next tile
        __builtin_amdgcn_s_setprio(1);
#pragma unroll
        for (int m = 0; m < 4; ++m)
#pragma unroll
            for (int ni = 0; ni < 4; ++ni)
                acc[4 + m][ni] = __builtin_amdgcn_mfma_f32_16x16x32_bf16(a3[m], b2[ni], acc[4 + m][ni], 0, 0, 0);
        __builtin_amdgcn_s_setprio(0);
    };

    for (int tt = 0; tt < NKT; tt += 2) {
        __builtin_amdgcn_s_barrier();   // TOP of even tile
        SB();
        tile(IC<0>{}, tt);
        __builtin_amdgcn_s_barrier();   // TOP of odd tile
        SB();
        tile(IC<1>{}, tt + 1);
    }
#undef WAITV
#undef WAITL

    // ---- Drain ALL in-flight asm loads (final ghost A0' prefetch!) before
    // the epilogue so the allocator may safely reuse their dst registers.
    asm volatile("s_waitcnt vmcnt(0) lgkmcnt(0)" ::: "memory");
    SB();

    // Epilogue. C/D layout: col = lane&15, row = quad*4 + reg (m89-verified).
#pragma unroll
    for (int ni = 0; ni < 4; ++ni) {
        const int lcol = wn * 64 + ni * 16 + l16;
        const int gcol = col0 + lcol;
        const float bv = bias_s[lcol];
        const int   rv = rc_s[lcol];
#pragma unroll
        for (int mi = 0; mi < 8; ++mi) {
            const int grow0 = row0 + wm * 128 + mi * 16 + quad * 4;
            u16x4 xq = *(const u16x4*)(xbT + (size_t)rv * B_ROWS + grow0);
#pragma unroll
            for (int r = 0; r < 4; ++r) {
                float v = fmaxf(acc[mi][ni][r] + bv, 0.0f) + bf2f(xq[r]);
                out[(size_t)(grow0 + r) * OUT_F + gcol] = v;
            }
        }
    }
}

extern "C" void kernel_launch(void* const* d_in, const int* in_sizes, int n_in,
                              void* d_out, int out_size, void* d_ws, size_t ws_size,
                              hipStream_t stream) {
    const float* x    = (const float*)d_in[0];
    const float* w    = (const float*)d_in[1];
    const float* bias = (const float*)d_in[2];
    const void*  mask = (const void*)d_in[3];
    const int*   rc   = (const int*)d_in[4];
    float* out = (float*)d_out;

    uint16_t* xb   = (uint16_t*)d_ws;                      // 32 MB
    uint16_t* wb   = xb  + (size_t)B_ROWS * IN_F;          // 32 MB
    uint16_t* xbT  = wb  + (size_t)OUT_F * IN_F;           // 32 MB

    prep_kernel<<<4096 + 2048, 256, 0, stream>>>(x, xb, xbT, w, mask, wb);

    gemm_kernel<<<dim3((B_ROWS / BM) * (OUT_F / BN)), dim3(512), 0, stream>>>(
        xb, wb, xbT, bias, rc, out);
}

// Round 9
// 335.586 us; speedup vs baseline: 1.5256x; 1.5256x over previous
//
#include <hip/hip_runtime.h>
#include <hip/hip_bf16.h>
#include <stdint.h>

#define B_ROWS 4096
#define IN_F   4096
#define OUT_F  4096

// 256x256 tile, K-step 64, 16 waves (1024 threads), 4M x 4N waves.
#define BM 256
#define BN 256
#define BK 64
#define NKT (IN_F / BK)   // 64 K-tiles

typedef float  f32x4  __attribute__((ext_vector_type(4)));
typedef short  bf16x8 __attribute__((ext_vector_type(8)));
typedef unsigned short u16x4 __attribute__((ext_vector_type(4)));

#define AS1 __attribute__((address_space(1)))
#define AS3 __attribute__((address_space(3)))

template<int N> struct IC { static constexpr int v = N; };

__device__ __forceinline__ uint16_t f2bf_rne(float f) {
    uint32_t u = __float_as_uint(f);
    uint32_t r = u + 0x7fffu + ((u >> 16) & 1u);
    return (uint16_t)(r >> 16);
}
__device__ __forceinline__ float bf2f(uint16_t h) {
    return __uint_as_float(((uint32_t)h) << 16);
}

// ---------------------------------------------------------------------------
// Fused prep (R5 v3, unchanged — known good):
//   blocks [0, 4096):     x fp32 -> xb bf16 [b][k] and xbT bf16 [k][b]
//   blocks [4096, 6144):  w fp32 + mask -> masked bf16 wb, grid-stride
// ---------------------------------------------------------------------------
__global__ __launch_bounds__(256) void prep_kernel(
    const float* __restrict__ x, uint16_t* __restrict__ xb, uint16_t* __restrict__ xbT,
    const float* __restrict__ w, const void* __restrict__ mraw, uint16_t* __restrict__ wb)
{
    const int tid = threadIdx.x;
    const int blk = blockIdx.x;

    if (blk < 4096) {
        __shared__ float t[64][65];
        const int r0 = (blk >> 6) * 64;   // batch rows
        const int c0 = (blk & 63) * 64;   // feature cols
        const int lr = tid >> 4;          // 0..15
        const int lc4 = (tid & 15) * 4;   // 0..60

#pragma unroll
        for (int p = 0; p < 4; ++p) {
            const int row = p * 16 + lr;
            float4 v = *(const float4*)(x + (size_t)(r0 + row) * IN_F + c0 + lc4);
            ushort4 o;
            o.x = f2bf_rne(v.x); o.y = f2bf_rne(v.y);
            o.z = f2bf_rne(v.z); o.w = f2bf_rne(v.w);
            *(ushort4*)(xb + (size_t)(r0 + row) * IN_F + c0 + lc4) = o;
            t[row][lc4 + 0] = v.x; t[row][lc4 + 1] = v.y;
            t[row][lc4 + 2] = v.z; t[row][lc4 + 3] = v.w;
        }
        __syncthreads();
#pragma unroll
        for (int p = 0; p < 4; ++p) {
            const int c = p * 16 + lr;    // source col -> dest row
            ushort4 o;
            o.x = f2bf_rne(t[lc4 + 0][c]);
            o.y = f2bf_rne(t[lc4 + 1][c]);
            o.z = f2bf_rne(t[lc4 + 2][c]);
            o.w = f2bf_rne(t[lc4 + 3][c]);
            *(ushort4*)(xbT + (size_t)(c0 + c) * B_ROWS + r0 + lc4) = o;
        }
    } else {
        __shared__ int wflag[4];
        uint32_t mword = ((const uint32_t*)mraw)[tid];           // words 0..255, L2-hot
        unsigned long long bal = __ballot((mword & 0xFFFFFF00u) != 0);
        if ((tid & 63) == 0) wflag[tid >> 6] = (bal != 0ull);
        __syncthreads();
        const int flag = wflag[0] | wflag[1] | wflag[2] | wflag[3];

        // grid-stride over 8192 chunks of 2048 elems; 2048 blocks -> 4 iters.
#pragma unroll
        for (int it = 0; it < 4; ++it) {
            const size_t c = (size_t)(blk - 4096) + (size_t)it * 2048;
            const size_t e = c * 2048 + (size_t)tid * 8;
            float4 v0 = *(const float4*)(w + e);
            float4 v1 = *(const float4*)(w + e + 4);
            int m[8];
            if (flag) {   // 1-byte bool mask
                uint2 mm = *(const uint2*)((const uint8_t*)mraw + e);
#pragma unroll
                for (int j = 0; j < 4; ++j) m[j]     = (mm.x >> (8 * j)) & 0xff;
#pragma unroll
                for (int j = 0; j < 4; ++j) m[4 + j] = (mm.y >> (8 * j)) & 0xff;
            } else {      // int32 0/1 mask
                const int* mp = (const int*)mraw + e;
                int4 a = *(const int4*)mp;
                int4 b = *(const int4*)(mp + 4);
                m[0] = a.x; m[1] = a.y; m[2] = a.z; m[3] = a.w;
                m[4] = b.x; m[5] = b.y; m[6] = b.z; m[7] = b.w;
            }
            bf16x8 o;
            o[0] = m[0] ? (short)f2bf_rne(v0.x) : (short)0;
            o[1] = m[1] ? (short)f2bf_rne(v0.y) : (short)0;
            o[2] = m[2] ? (short)f2bf_rne(v0.z) : (short)0;
            o[3] = m[3] ? (short)f2bf_rne(v0.w) : (short)0;
            o[4] = m[4] ? (short)f2bf_rne(v1.x) : (short)0;
            o[5] = m[5] ? (short)f2bf_rne(v1.y) : (short)0;
            o[6] = m[6] ? (short)f2bf_rne(v1.z) : (short)0;
            o[7] = m[7] ? (short)f2bf_rne(v1.w) : (short)0;
            *(bf16x8*)(wb + e) = o;
        }
    }
}

// ds_read_b128 with compile-time offset immediate; early-clobber dst
// (R7 lesson: dst must never alias the in-flight address operand).
#define DSR(dst, base, OFS) \
    asm volatile("ds_read_b128 %0, %1 offset:" #OFS : "=&v"(dst) : "v"(base))
#define LDSOFF(p) ((uint32_t)(uintptr_t)(AS3 void*)(p))
#define SB() __builtin_amdgcn_sched_barrier(0)

// ---------------------------------------------------------------------------
// 256x256x64 GEMM, 16 waves (4 waves/SIMD), both operands LDS-staged.
// C[b,o] = relu( sum_k xb[b,k]*wb[o,k] + bias[o] ) + xbT[rc[o]][b]
//
// R8 post-mortem: A-from-global refuted (16-way segmented wave loads ->
// 297us). R5's plateau re-diagnosed as TLP starvation: MfmaUtil 45 +
// VALU 17 + LDS ~37 ~ 100% -> pipes ALTERNATE; at 2 waves/SIMD, when both
// waves wait on lgkm the SIMD idles. Fix: same tile/addressing as R5, but
// 1024 threads = 16 waves = 4 waves/SIMD (4M x 4N, 64x64 out/wave,
// acc = 64 VGPR). Schedule is intentionally simple (m97 mechanism:
// occupancy does the overlap): per K-tile, one vmcnt(0)+barrier (stages
// are a full tile old -> free), then 2x { issue 8 ds_reads; lgkm(0);
// setprio; 16 MFMA }. __launch_bounds__(1024,4) pins VGPR<=128.
//
// LDS: A/B each [2][256x64] linear (global_load_lds, rule 21); XOR-swizzle
// pair unchanged from R3/R5 (measured-zero conflicts): 16B-chunk slot s of
// row r holds global k-chunk s^(r&7); reads use e0=(quad*8)^((l16&7)*8).
// 4 stage loads/thread/tile (1024 thr x 4 x 16B = 64KB = A+B tile).
// ---------------------------------------------------------------------------
__global__ __launch_bounds__(1024, 4) void gemm_kernel(
    const uint16_t* __restrict__ xb, const uint16_t* __restrict__ wb,
    const uint16_t* __restrict__ xbT, const float* __restrict__ bias,
    const int* __restrict__ rc, float* __restrict__ out)
{
    __shared__ alignas(16) uint16_t Ab[2][256 * BK];   // 64 KB
    __shared__ alignas(16) uint16_t Bb[2][256 * BK];   // 64 KB
    __shared__ float bias_s[BN];
    __shared__ int   rc_s[BN];

    const int tid = threadIdx.x;

    // XCD-aware bijective swizzle: 256 blocks, 8 XCDs.
    const int bid = blockIdx.x;
    const int wg  = (bid & 7) * 32 + (bid >> 3);
    const int row0 = (wg >> 4) * BM;
    const int col0 = (wg & 15) * BN;

    const int wave = tid >> 6, lane = tid & 63;
    const int wm = wave >> 2;          // 0..3 : 64-row slice
    const int wn = wave & 3;           // 0..3 : 64-col slice
    const int quad = lane >> 4, l16 = lane & 15;
    const int swr = (l16 & 7) << 3;
    const int e0  = (quad << 3) ^ swr;                    // elem offset, ks=0
    const uint32_t kd = (uint32_t)(((e0 ^ 32) - e0) * 2); // byte delta ks0->ks1

    // Per-parity LDS read bases (verified conflict-free pattern:
    // row&7 == l16&7 matches the staged slot^(row&7) layout).
    const uint32_t aB0 = LDSOFF(&Ab[0][0]) + (uint32_t)(((wm * 64 + l16) * BK + e0) * 2);
    const uint32_t aB1 = LDSOFF(&Ab[1][0]) + (uint32_t)(((wm * 64 + l16) * BK + e0) * 2);
    const uint32_t bB0 = LDSOFF(&Bb[0][0]) + (uint32_t)(((wn * 64 + l16) * BK + e0) * 2);
    const uint32_t bB1 = LDSOFF(&Bb[1][0]) + (uint32_t)(((wn * 64 + l16) * BK + e0) * 2);

    // Staging source (pre-swizzled global address, rule 21): 1024 threads,
    // chunk c = tid (+1024); row = c>>3 (0..127, +128), slot = c&7,
    // source k-chunk = slot^(row&7)  ((row+128)&7 == row&7 -> same ssw).
    const int srow = tid >> 3;                              // 0..127
    const int ssw  = ((tid & 7) ^ (srow & 7)) << 3;         // element offset
    const uint16_t* pA = xb + (size_t)(row0 + srow) * IN_F + ssw;
    const uint16_t* pB = wb + (size_t)(col0 + srow) * IN_F + ssw;

    auto stage = [&](const uint16_t* src, uint16_t* ldsdst, size_t ko) {
        __builtin_amdgcn_global_load_lds((const AS1 void*)(src + ko),
                                         (AS3 void*)(ldsdst + tid * 8), 16, 0, 0);
        __builtin_amdgcn_global_load_lds((const AS1 void*)(src + ko + (size_t)128 * IN_F),
                                         (AS3 void*)(ldsdst + tid * 8 + 8192), 16, 0, 0);
    };

    // bias/rc -> LDS (retired by the prologue vmcnt(0)).
    if (tid < BN) {
        __builtin_amdgcn_global_load_lds((const AS1 void*)(bias + col0 + tid),
                                         (AS3 void*)(bias_s + tid), 4, 0, 0);
        __builtin_amdgcn_global_load_lds((const AS1 void*)(rc + col0 + tid),
                                         (AS3 void*)(rc_s + tid), 4, 0, 0);
    }

    f32x4 acc[4][4];   // [mi][ni] — 64 VGPR
#pragma unroll
    for (int mi = 0; mi < 4; ++mi)
#pragma unroll
        for (int ni = 0; ni < 4; ++ni)
            acc[mi][ni] = (f32x4){0.f, 0.f, 0.f, 0.f};

    // Prologue: stage tile 0; drain; barrier.
    stage(pA, &Ab[0][0], 0);
    stage(pB, &Bb[0][0], 0);
    asm volatile("s_waitcnt vmcnt(0)" ::: "memory");
    SB();
    __builtin_amdgcn_s_barrier();

#define LGKM0() do { asm volatile("s_waitcnt lgkmcnt(0)" ::: "memory"); SB(); } while (0)

    auto tile = [&](auto curc, int t) {
        constexpr int CUR = decltype(curc)::v;
        constexpr int NXT = CUR ^ 1;
        const uint32_t aB = CUR ? aB1 : aB0;
        const uint32_t bB = CUR ? bB1 : bB0;
        // t = NKT-1 stages one garbage K-tile past the end; lands in the
        // adjacent workspace region (wb / xbT), never consumed.
        const size_t koff = (size_t)(t + 1) * BK;

        bf16x8 a[4], b[4];

        // ---- ks0: issue reads + all stages of t+1, drain lgkm, 16 MFMA.
        DSR(b[0], bB, 0); DSR(b[1], bB, 2048); DSR(b[2], bB, 4096); DSR(b[3], bB, 6144);
        DSR(a[0], aB, 0); DSR(a[1], aB, 2048); DSR(a[2], aB, 4096); DSR(a[3], aB, 6144);
        stage(pA, &Ab[NXT][0], koff);
        stage(pB, &Bb[NXT][0], koff);
        LGKM0();
        __builtin_amdgcn_s_setprio(1);
#pragma unroll
        for (int m = 0; m < 4; ++m)
#pragma unroll
            for (int ni = 0; ni < 4; ++ni)
                acc[m][ni] = __builtin_amdgcn_mfma_f32_16x16x32_bf16(a[m], b[ni], acc[m][ni], 0, 0, 0);
        __builtin_amdgcn_s_setprio(0);

        // ---- ks1.
        DSR(b[0], bB + kd, 0); DSR(b[1], bB + kd, 2048); DSR(b[2], bB + kd, 4096); DSR(b[3], bB + kd, 6144);
        DSR(a[0], aB + kd, 0); DSR(a[1], aB + kd, 2048); DSR(a[2], aB + kd, 4096); DSR(a[3], aB + kd, 6144);
        LGKM0();
        __builtin_amdgcn_s_setprio(1);
#pragma unroll
        for (int m = 0; m < 4; ++m)
#pragma unroll
            for (int ni = 0; ni < 4; ++ni)
                acc[m][ni] = __builtin_amdgcn_mfma_f32_16x16x32_bf16(a[m], b[ni], acc[m][ni], 0, 0, 0);
        __builtin_amdgcn_s_setprio(0);

        // ---- tile boundary: stages for t+1 were issued at the top of this
        // tile (~one full tile of MFMA+LDS ago) -> vmcnt(0) is ~free.
        asm volatile("s_waitcnt vmcnt(0)" ::: "memory");
        SB();
        __builtin_amdgcn_s_barrier();
        SB();
    };

    for (int tt = 0; tt < NKT; tt += 2) {
        tile(IC<0>{}, tt);
        tile(IC<1>{}, tt + 1);
    }
#undef LGKM0

    // Drain any in-flight loads before the epilogue reuses registers.
    asm volatile("s_waitcnt vmcnt(0) lgkmcnt(0)" ::: "memory");
    SB();

    // Epilogue. C/D layout: col = lane&15, row = quad*4 + reg (m89-verified).
#pragma unroll
    for (int ni = 0; ni < 4; ++ni) {
        const int lcol = wn * 64 + ni * 16 + l16;
        const int gcol = col0 + lcol;
        const float bv = bias_s[lcol];
        const int   rv = rc_s[lcol];
#pragma unroll
        for (int mi = 0; mi < 4; ++mi) {
            const int grow0 = row0 + wm * 64 + mi * 16 + quad * 4;
            u16x4 xq = *(const u16x4*)(xbT + (size_t)rv * B_ROWS + grow0);
#pragma unroll
            for (int r = 0; r < 4; ++r) {
                float v = fmaxf(acc[mi][ni][r] + bv, 0.0f) + bf2f(xq[r]);
                out[(size_t)(grow0 + r) * OUT_F + gcol] = v;
            }
        }
    }
}

extern "C" void kernel_launch(void* const* d_in, const int* in_sizes, int n_in,
                              void* d_out, int out_size, void* d_ws, size_t ws_size,
                              hipStream_t stream) {
    const float* x    = (const float*)d_in[0];
    const float* w    = (const float*)d_in[1];
    const float* bias = (const float*)d_in[2];
    const void*  mask = (const void*)d_in[3];
    const int*   rc   = (const int*)d_in[4];
    float* out = (float*)d_out;

    uint16_t* xb   = (uint16_t*)d_ws;                      // 32 MB
    uint16_t* wb   = xb  + (size_t)B_ROWS * IN_F;          // 32 MB
    uint16_t* xbT  = wb  + (size_t)OUT_F * IN_F;           // 32 MB

    prep_kernel<<<4096 + 2048, 256, 0, stream>>>(x, xb, xbT, w, mask, wb);

    gemm_kernel<<<dim3((B_ROWS / BM) * (OUT_F / BN)), dim3(1024), 0, stream>>>(
        xb, wb, xbT, bias, rc, out);
}